// Round 10
// baseline (369.294 us; speedup 1.0000x reference)
//
#include <hip/hip_runtime.h>

#define BB 16      // batch
#define CC 64      // channels (Cin = Cout = 64)
#define HH 128
#define WW 128
#define MM 67      // modes per axis
#define MODES (MM*MM)   // 4489
#define MC 32      // mode chunk for mix
#define NCHUNK 141 // ceil(4489/32)

typedef float f4 __attribute__((ext_vector_type(4)));

__constant__ float DEC_LO[8] = {-0.010597401784997278f, 0.032883011666982945f, 0.030841381835986965f,
                                -0.18703481171888114f, -0.02798376941698385f, 0.6308807679295904f,
                                0.7148465705525415f, 0.23037781330885523f};
__constant__ float DEC_HI[8] = {-0.23037781330885523f, 0.7148465705525415f, -0.6308807679295904f,
                                -0.02798376941698385f, 0.18703481171888114f, 0.030841381835986965f,
                                -0.032883011666982945f, -0.010597401784997278f};

// ---------------- analysis along W: x (B,C,H,W) -> t1 (B,C,2,H,67) ----------------
__global__ __launch_bounds__(256) void dwt_w(const float* __restrict__ x, float* __restrict__ t1) {
    __shared__ float row[8][128];
    const int bc = blockIdx.x;           // 0..1023
    const int h0 = blockIdx.y * 8;       // 0..120
    const int t  = threadIdx.x;
    {
        int r = t >> 5, c = (t & 31) << 2;
        const float4 v = *(const float4*)&x[((size_t)bc * HH + h0 + r) * WW + c];
        row[r][c] = v.x; row[r][c+1] = v.y; row[r][c+2] = v.z; row[r][c+3] = v.w;
    }
    __syncthreads();
    for (int oidx = t; oidx < 8 * 2 * MM; oidx += 256) {
        int wo = oidx % MM;
        int f  = (oidx / MM) & 1;
        int r  = oidx / (2 * MM);
        const float* flt = f ? DEC_HI : DEC_LO;
        float acc = 0.f;
        int base = 2 * wo - 6;
        #pragma unroll
        for (int k = 0; k < 8; ++k) {
            int i = base + k;
            i = (i < 0) ? (-i - 1) : i;
            i = (i >= WW) ? (2 * WW - 1 - i) : i;
            acc += row[r][i] * flt[7 - k];
        }
        t1[(((size_t)bc * 2 + f) * HH + h0 + r) * MM + wo] = acc;
    }
}

// ---------------- analysis along H: t1 -> coeff (B,C,4,67,67), band = fw*2+fh ------
__global__ __launch_bounds__(256) void dwt_h(const float* __restrict__ t1, float* __restrict__ cf) {
    const int NH2 = (MM + 1) / 2;  // 34 ho-pairs
    int idx = blockIdx.x * 256 + threadIdx.x;
    const int N = BB * CC * 2 * NH2 * MM;
    if (idx >= N) return;
    int wo = idx % MM;
    int hp = (idx / MM) % NH2;
    int fw = (idx / (MM * NH2)) % 2;
    int bc = idx / (MM * NH2 * 2);
    const float* src = t1 + ((size_t)(bc * 2 + fw) * HH) * MM + wo;
    float rv[10];
    #pragma unroll
    for (int k = 0; k < 10; ++k) {
        int i = 4 * hp - 6 + k;
        i = (i < 0) ? (-i - 1) : i;
        i = (i >= HH) ? (2 * HH - 1 - i) : i;
        rv[k] = src[(size_t)i * MM];
    }
    float lo0 = 0.f, hi0 = 0.f, lo1 = 0.f, hi1 = 0.f;
    #pragma unroll
    for (int k = 0; k < 8; ++k) {
        lo0 += rv[k]     * DEC_LO[7 - k];
        hi0 += rv[k]     * DEC_HI[7 - k];
        lo1 += rv[k + 2] * DEC_LO[7 - k];
        hi1 += rv[k + 2] * DEC_HI[7 - k];
    }
    int ho0 = 2 * hp, ho1 = 2 * hp + 1;
    size_t b0 = (size_t)(bc * 4 + fw * 2 + 0) * MM;
    size_t b1 = (size_t)(bc * 4 + fw * 2 + 1) * MM;
    cf[(b0 + ho0) * MM + wo] = lo0;
    cf[(b1 + ho0) * MM + wo] = hi0;
    if (ho1 < MM) {
        cf[(b0 + ho1) * MM + wo] = lo1;
        cf[(b1 + ho1) * MM + wo] = hi1;
    }
}

// ---------------- per-mode channel mix ----------------
// out[b,o,band,m] = sum_i cf[b,i,band,m] * w_band[i,o,m]
// Block = (b-half 8, band, 32-mode chunk): coeff tile 8b x 64i x 32m = 64 KB LDS
// => 2 blocks/CU x 8 waves = 4 waves/SIMD. TLP (not register pipelining, which
// hipcc collapses — rounds 6/8/9) hides the weight-load latency.
// Thread = 2b x 4o x 4m: per i = 4 weight f4 VMEM + 2 coeff LDS broadcasts
// (8-lane same-addr groups, conflict-free) + 8 f4 FMA. acc 32 VGPR.
// Weights read by 2 blocks (the two b-halves) — L2/L3 absorbs, HBM once.
__global__ __launch_bounds__(512, 4) void mix_k(const float* __restrict__ cf,
                                                const float* __restrict__ w1,
                                                const float* __restrict__ w2,
                                                const float* __restrict__ w3,
                                                const float* __restrict__ w4,
                                                float* __restrict__ out) {
    __shared__ float sc[8][CC][MC];   // coeff [b-local][i][m]  64 KB
    // --- bijective XCD swizzle; NWG = 141*4*2 = 1128 = 8*141 exactly ---
    int flat = (blockIdx.z * 4 + blockIdx.y) * NCHUNK + blockIdx.x;
    flat = (flat & 7) * NCHUNK + (flat >> 3);          // 1128 % 8 == 0 -> simple form
    const int bh   = flat / (NCHUNK * 4);              // b-half: 0 or 1
    const int band = (flat / NCHUNK) & 3;
    const int m0   = min((flat % NCHUNK) * MC, MODES - MC);  // last chunks overlap (identical values)
    const int tid  = threadIdx.x;
    const float* w = (band == 0) ? w1 : (band == 1) ? w2 : (band == 2) ? w3 : w4;
    const int bg0 = bh * 8;                            // first global batch of this half

    // ---- stage coeff tile: 512 rows (8b x 64i) x 32 floats, 512 threads ----
    {
        const int c = tid & 7, r0 = tid >> 3;          // 8 threads/row (f4 each)
        #pragma unroll
        for (int p = 0; p < 8; ++p) {
            int r = r0 + (p << 6);                     // 0..511
            int b = bg0 + (r >> 6), i = r & 63;
            f4 v = *(const f4*)(cf + ((size_t)((b * CC + i) * 4) + band) * MODES + m0 + c * 4);
            *(f4*)&sc[r >> 6][i][c * 4] = v;
        }
    }
    __syncthreads();

    const int lane = tid & 63, wv = tid >> 6;
    const int bq   = (wv & 3) * 2;                      // local batch pair: 0,2,4,6
    const int os   = (wv >> 2) * 32 + (lane >> 3) * 4;  // first of 4 consecutive o
    const int mc4f = (lane & 7) * 4;                    // float offset of the 4 modes
    const size_t IST = (size_t)CC * MODES;
    const float* wp = w + (size_t)os * MODES + m0 + mc4f;   // + k*MODES per o, + i*IST per i

    f4 acc[2][4];   // [b][o]
    #pragma unroll
    for (int j = 0; j < 2; ++j)
        #pragma unroll
        for (int k = 0; k < 4; ++k) acc[j][k] = (f4)(0.f);

    f4 wa0, wa1, wa2, wa3, wb0, wb1, wb2, wb3;
    wa0 = *(const f4*)(wp + 0 * MODES);
    wa1 = *(const f4*)(wp + 1 * MODES);
    wa2 = *(const f4*)(wp + 2 * MODES);
    wa3 = *(const f4*)(wp + 3 * MODES);

    #pragma unroll 1
    for (int i = 0; i < CC; i += 2) {
        {
            const float* p1 = wp + (size_t)(i + 1) * IST;
            wb0 = *(const f4*)(p1 + 0 * MODES);
            wb1 = *(const f4*)(p1 + 1 * MODES);
            wb2 = *(const f4*)(p1 + 2 * MODES);
            wb3 = *(const f4*)(p1 + 3 * MODES);
        }
        {
            f4 s0 = *(const f4*)&sc[bq + 0][i][mc4f];
            f4 s1 = *(const f4*)&sc[bq + 1][i][mc4f];
            acc[0][0] += s0 * wa0;  acc[0][1] += s0 * wa1;  acc[0][2] += s0 * wa2;  acc[0][3] += s0 * wa3;
            acc[1][0] += s1 * wa0;  acc[1][1] += s1 * wa1;  acc[1][2] += s1 * wa2;  acc[1][3] += s1 * wa3;
        }
        if (i + 2 < CC) {
            const float* p2 = wp + (size_t)(i + 2) * IST;
            wa0 = *(const f4*)(p2 + 0 * MODES);
            wa1 = *(const f4*)(p2 + 1 * MODES);
            wa2 = *(const f4*)(p2 + 2 * MODES);
            wa3 = *(const f4*)(p2 + 3 * MODES);
        }
        {
            f4 s0 = *(const f4*)&sc[bq + 0][i + 1][mc4f];
            f4 s1 = *(const f4*)&sc[bq + 1][i + 1][mc4f];
            acc[0][0] += s0 * wb0;  acc[0][1] += s0 * wb1;  acc[0][2] += s0 * wb2;  acc[0][3] += s0 * wb3;
            acc[1][0] += s1 * wb0;  acc[1][1] += s1 * wb1;  acc[1][2] += s1 * wb2;  acc[1][3] += s1 * wb3;
        }
    }

    #pragma unroll
    for (int j = 0; j < 2; ++j)
        #pragma unroll
        for (int k = 0; k < 4; ++k)
            *(f4*)&out[((size_t)(((bg0 + bq + j) * CC + os + k) * 4) + band) * MODES + m0 + mc4f] = acc[j][k];
}

// ---------------- synthesis along H: mixed (B,C,4,67,67) -> u1 (B,C,2,128,67) ------
__global__ __launch_bounds__(256) void idwt_h(const float* __restrict__ mx, float* __restrict__ u1) {
    int idx = blockIdx.x * 256 + threadIdx.x;
    const int N = BB * CC * 2 * (HH / 2) * MM;
    if (idx >= N) return;
    int wo = idx % MM;
    int a  = (idx / MM) % (HH / 2);
    int fw = (idx / (MM * (HH / 2))) % 2;
    int bc = idx / (MM * (HH / 2) * 2);
    const float* lo = mx + ((size_t)(bc * 4 + fw * 2) * MODES) + wo;
    const float* hi = lo + MODES;
    float l[4], h4[4];
    #pragma unroll
    for (int q = 0; q < 4; ++q) {
        l[q]  = lo[(size_t)(a + q) * MM];
        h4[q] = hi[(size_t)(a + q) * MM];
    }
    float out0 = 0.f, out1 = 0.f;
    #pragma unroll
    for (int q = 0; q < 4; ++q) {
        out0 += l[q] * DEC_LO[2 * q + 1] + h4[q] * DEC_HI[2 * q + 1];  // h = 2a
        out1 += l[q] * DEC_LO[2 * q]     + h4[q] * DEC_HI[2 * q];      // h = 2a+1
    }
    size_t base = ((size_t)(bc * 2 + fw) * HH + 2 * a) * MM + wo;
    u1[base]      = out0;
    u1[base + MM] = out1;
}

// ---------------- synthesis along W: u1 -> out (B,C,128,128) ----------------
__global__ __launch_bounds__(256) void idwt_w(const float* __restrict__ u1, float* __restrict__ out) {
    int idx = blockIdx.x * 256 + threadIdx.x;
    const int N = BB * CC * HH * (WW / 2);
    if (idx >= N) return;
    int a  = idx % (WW / 2);
    int h  = (idx / (WW / 2)) % HH;
    int bc = idx / ((WW / 2) * HH);
    const float* lo = u1 + (size_t)(bc * 2) * HH * MM + (size_t)h * MM;
    const float* hi = lo + (size_t)HH * MM;
    float l[4], h4[4];
    #pragma unroll
    for (int q = 0; q < 4; ++q) {
        l[q]  = lo[a + q];
        h4[q] = hi[a + q];
    }
    float out0 = 0.f, out1 = 0.f;
    #pragma unroll
    for (int q = 0; q < 4; ++q) {
        out0 += l[q] * DEC_LO[2 * q + 1] + h4[q] * DEC_HI[2 * q + 1];  // n = 2a
        out1 += l[q] * DEC_LO[2 * q]     + h4[q] * DEC_HI[2 * q];      // n = 2a+1
    }
    float2 r = make_float2(out0, out1);
    *(float2*)&out[((size_t)bc * HH + h) * WW + 2 * a] = r;
}

extern "C" void kernel_launch(void* const* d_in, const int* in_sizes, int n_in,
                              void* d_out, int out_size, void* d_ws, size_t ws_size,
                              hipStream_t stream) {
    const float* x  = (const float*)d_in[0];
    const float* w1 = (const float*)d_in[1];
    const float* w2 = (const float*)d_in[2];
    const float* w3 = (const float*)d_in[3];
    const float* w4 = (const float*)d_in[4];
    float* out = (float*)d_out;

    const size_t COEFF_FLTS = (size_t)BB * CC * 4 * MODES;
    float* buf1 = (float*)d_ws;
    float* buf2 = buf1 + COEFF_FLTS;

    // 1) DWT along W: x -> buf1 (t1)
    {
        dim3 grid(BB * CC, HH / 8);
        dwt_w<<<grid, 256, 0, stream>>>(x, buf1);
    }
    // 2) DWT along H: buf1 -> buf2 (coeff)
    {
        int N = BB * CC * 2 * ((MM + 1) / 2) * MM;
        dwt_h<<<(N + 255) / 256, 256, 0, stream>>>(buf1, buf2);
    }
    // 3) per-mode channel mixing: buf2 -> buf1 (mixed)
    {
        dim3 grid(NCHUNK, 4, 2);   // (141 mode-chunks, 4 bands, 2 b-halves)
        mix_k<<<grid, 512, 0, stream>>>(buf2, w1, w2, w3, w4, buf1);
    }
    // 4) inverse DWT along H: buf1 -> buf2 (u1)
    {
        int N = BB * CC * 2 * (HH / 2) * MM;
        idwt_h<<<(N + 255) / 256, 256, 0, stream>>>(buf1, buf2);
    }
    // 5) inverse DWT along W: buf2 -> d_out
    {
        int N = BB * CC * HH * (WW / 2);
        idwt_w<<<(N + 255) / 256, 256, 0, stream>>>(buf2, out);
    }
}

// Round 11
// 295.850 us; speedup vs baseline: 1.2482x; 1.2482x over previous
//
#include <hip/hip_runtime.h>

#define BB 16      // batch
#define CC 64      // channels (Cin = Cout = 64)
#define HH 128
#define WW 128
#define MM 67      // modes per axis
#define MODES (MM*MM)   // 4489
#define MC 32      // mode chunk for mix
#define NCHUNK 141 // ceil(4489/32)

typedef float f4 __attribute__((ext_vector_type(4)));

#define AS1 __attribute__((address_space(1)))
#define AS3 __attribute__((address_space(3)))

__constant__ float DEC_LO[8] = {-0.010597401784997278f, 0.032883011666982945f, 0.030841381835986965f,
                                -0.18703481171888114f, -0.02798376941698385f, 0.6308807679295904f,
                                0.7148465705525415f, 0.23037781330885523f};
__constant__ float DEC_HI[8] = {-0.23037781330885523f, 0.7148465705525415f, -0.6308807679295904f,
                                -0.02798376941698385f, 0.18703481171888114f, 0.030841381835986965f,
                                -0.032883011666982945f, -0.010597401784997278f};

// ---------------- analysis along W: x (B,C,H,W) -> t1 (B,C,2,H,67) ----------------
__global__ __launch_bounds__(256) void dwt_w(const float* __restrict__ x, float* __restrict__ t1) {
    __shared__ float row[8][128];
    const int bc = blockIdx.x;           // 0..1023
    const int h0 = blockIdx.y * 8;       // 0..120
    const int t  = threadIdx.x;
    {
        int r = t >> 5, c = (t & 31) << 2;
        const float4 v = *(const float4*)&x[((size_t)bc * HH + h0 + r) * WW + c];
        row[r][c] = v.x; row[r][c+1] = v.y; row[r][c+2] = v.z; row[r][c+3] = v.w;
    }
    __syncthreads();
    for (int oidx = t; oidx < 8 * 2 * MM; oidx += 256) {
        int wo = oidx % MM;
        int f  = (oidx / MM) & 1;
        int r  = oidx / (2 * MM);
        const float* flt = f ? DEC_HI : DEC_LO;
        float acc = 0.f;
        int base = 2 * wo - 6;
        #pragma unroll
        for (int k = 0; k < 8; ++k) {
            int i = base + k;
            i = (i < 0) ? (-i - 1) : i;
            i = (i >= WW) ? (2 * WW - 1 - i) : i;
            acc += row[r][i] * flt[7 - k];
        }
        t1[(((size_t)bc * 2 + f) * HH + h0 + r) * MM + wo] = acc;
    }
}

// ---------------- analysis along H: t1 -> coeff (B,C,4,67,67), band = fw*2+fh ------
__global__ __launch_bounds__(256) void dwt_h(const float* __restrict__ t1, float* __restrict__ cf) {
    const int NH2 = (MM + 1) / 2;  // 34 ho-pairs
    int idx = blockIdx.x * 256 + threadIdx.x;
    const int N = BB * CC * 2 * NH2 * MM;
    if (idx >= N) return;
    int wo = idx % MM;
    int hp = (idx / MM) % NH2;
    int fw = (idx / (MM * NH2)) % 2;
    int bc = idx / (MM * NH2 * 2);
    const float* src = t1 + ((size_t)(bc * 2 + fw) * HH) * MM + wo;
    float rv[10];
    #pragma unroll
    for (int k = 0; k < 10; ++k) {
        int i = 4 * hp - 6 + k;
        i = (i < 0) ? (-i - 1) : i;
        i = (i >= HH) ? (2 * HH - 1 - i) : i;
        rv[k] = src[(size_t)i * MM];
    }
    float lo0 = 0.f, hi0 = 0.f, lo1 = 0.f, hi1 = 0.f;
    #pragma unroll
    for (int k = 0; k < 8; ++k) {
        lo0 += rv[k]     * DEC_LO[7 - k];
        hi0 += rv[k]     * DEC_HI[7 - k];
        lo1 += rv[k + 2] * DEC_LO[7 - k];
        hi1 += rv[k + 2] * DEC_HI[7 - k];
    }
    int ho0 = 2 * hp, ho1 = 2 * hp + 1;
    size_t b0 = (size_t)(bc * 4 + fw * 2 + 0) * MM;
    size_t b1 = (size_t)(bc * 4 + fw * 2 + 1) * MM;
    cf[(b0 + ho0) * MM + wo] = lo0;
    cf[(b1 + ho0) * MM + wo] = hi0;
    if (ho1 < MM) {
        cf[(b0 + ho1) * MM + wo] = lo1;
        cf[(b1 + ho1) * MM + wo] = hi1;
    }
}

// ---------------- per-mode channel mix ----------------
// out[b,o,band,m] = sum_i cf[b,i,band,m] * w_band[i,o,m]
// Block = (band, 32-mode chunk), ALL b / i / o => zero-redundancy HBM fetch.
// coeff tile 16b x 64i x 32m = 128 KB LDS (broadcast reads, conflict-free).
// Weights stream through a 2-slot x 2-i LDS ring (32 KB) via global_load_lds
// DMA — no destination registers, so the prefetch cannot be sunk by the
// register allocator (the failure of rounds 6/8/10: VGPR counts 160/88/52
// prove hipcc serializes VGPR prefetch). T3 minimum-2-phase schedule:
// STAGE(next 2 i) -> compute (cur 2 i) -> __syncthreads (vmcnt0 drain = handoff).
// Per thread per i: 4 weight ds_read_b128 + 4 coeff broadcasts + 16 f4 FMA.
__global__ __launch_bounds__(512, 1) void mix_k(const float* __restrict__ cf,
                                                const float* __restrict__ w1,
                                                const float* __restrict__ w2,
                                                const float* __restrict__ w3,
                                                const float* __restrict__ w4,
                                                float* __restrict__ out) {
    __shared__ float sc[BB][CC][MC];      // coeff [b][i][m]       128 KB
    __shared__ float sw[2][2][CC][MC];    // weights [slot][i2][o][m]  32 KB  (total 160 KB)
    // --- bijective XCD swizzle over NWG = 141*4 = 564 = 8*70 + 4 ---
    int flat = blockIdx.y * NCHUNK + blockIdx.x;
    {
        const int q = 564 / 8, r = 564 % 8;          // 70, 4
        int xcd = flat & 7, j = flat >> 3;
        flat = (xcd < r ? xcd * (q + 1) : r * (q + 1) + (xcd - r) * q) + j;
    }
    const int band = flat / NCHUNK;
    const int m0   = min((flat % NCHUNK) * MC, MODES - MC);  // last chunks overlap (identical values)
    const int tid  = threadIdx.x;
    const int lane = tid & 63, wv = tid >> 6;
    const float* w = (band == 0) ? w1 : (band == 1) ? w2 : (band == 2) ? w3 : w4;

    // Stage weights for cin = i0, i0+1 into sw[slot]. 8 waves x 8 instrs x 256 B
    // = 16 KB. Wave wv covers i-half (wv>>2), o-rows (wv&3)*16..+15.
    // DMA dest is wave-uniform base; lane l writes byte l*4 => rows r,r+1 linear.
    #define STAGE_W(slot, i0)                                                              \
    {                                                                                      \
        const int _ih = wv >> 2, _ob = (wv & 3) * 16;                                      \
        const float* _srcb = w + ((size_t)((i0) + _ih) * CC + _ob) * MODES + m0;           \
        _Pragma("unroll")                                                                  \
        for (int _j = 0; _j < 8; ++_j) {                                                   \
            __builtin_amdgcn_global_load_lds(                                              \
                (const AS1 void*)(_srcb + (size_t)(2 * _j + (lane >> 5)) * MODES + (lane & 31)), \
                (AS3 void*)&sw[slot][_ih][_ob + 2 * _j][0], 4, 0, 0);                      \
        }                                                                                  \
    }

    STAGE_W(0, 0);   // prologue DMA overlaps the coeff staging below

    // ---- stage coeff tile: 1024 rows (b*64+i) x 32 floats, 512 threads ----
    {
        const int c = tid & 7, r0 = tid >> 3;        // 8 threads/row (f4 each)
        #pragma unroll
        for (int p = 0; p < 16; ++p) {
            int r = r0 + (p << 6);                   // 0..1023
            f4 v = *(const f4*)(cf + ((size_t)(r * 4) + band) * MODES + m0 + c * 4);
            *(f4*)&sc[r >> 6][r & 63][c * 4] = v;
        }
    }
    __syncthreads();   // drains coeff stores AND this wave's STAGE_W(0) DMA

    const int bq   = (wv & 3) * 4;                      // wave's batch quad
    const int os   = (wv >> 2) * 32 + (lane >> 3) * 4;  // first of 4 consecutive o
    const int mc4f = (lane & 7) * 4;                    // float offset of the 4 modes

    f4 acc[4][4];   // [b][o]
    #pragma unroll
    for (int j = 0; j < 4; ++j)
        #pragma unroll
        for (int k = 0; k < 4; ++k) acc[j][k] = (f4)(0.f);

    #pragma unroll 1
    for (int ip = 0; ip < 32; ++ip) {
        if (ip + 1 < 32) STAGE_W((ip + 1) & 1, 2 * (ip + 1));
        const int s = ip & 1;
        #pragma unroll
        for (int ii = 0; ii < 2; ++ii) {
            const int gi = 2 * ip + ii;
            f4 w0 = *(const f4*)&sw[s][ii][os + 0][mc4f];
            f4 w1v = *(const f4*)&sw[s][ii][os + 1][mc4f];
            f4 w2v = *(const f4*)&sw[s][ii][os + 2][mc4f];
            f4 w3v = *(const f4*)&sw[s][ii][os + 3][mc4f];
            f4 s0 = *(const f4*)&sc[bq + 0][gi][mc4f];
            f4 s1 = *(const f4*)&sc[bq + 1][gi][mc4f];
            f4 s2 = *(const f4*)&sc[bq + 2][gi][mc4f];
            f4 s3 = *(const f4*)&sc[bq + 3][gi][mc4f];
            acc[0][0] += s0 * w0;  acc[0][1] += s0 * w1v;  acc[0][2] += s0 * w2v;  acc[0][3] += s0 * w3v;
            acc[1][0] += s1 * w0;  acc[1][1] += s1 * w1v;  acc[1][2] += s1 * w2v;  acc[1][3] += s1 * w3v;
            acc[2][0] += s2 * w0;  acc[2][1] += s2 * w1v;  acc[2][2] += s2 * w2v;  acc[2][3] += s2 * w3v;
            acc[3][0] += s3 * w0;  acc[3][1] += s3 * w1v;  acc[3][2] += s3 * w2v;  acc[3][3] += s3 * w3v;
        }
        __syncthreads();   // vmcnt(0): next slot's DMA landed; also protects slot reuse
    }

    #pragma unroll
    for (int j = 0; j < 4; ++j)
        #pragma unroll
        for (int k = 0; k < 4; ++k)
            *(f4*)&out[((size_t)(((bq + j) * CC + os + k) * 4) + band) * MODES + m0 + mc4f] = acc[j][k];
    #undef STAGE_W
}

// ---------------- synthesis along H: mixed (B,C,4,67,67) -> u1 (B,C,2,128,67) ------
__global__ __launch_bounds__(256) void idwt_h(const float* __restrict__ mx, float* __restrict__ u1) {
    int idx = blockIdx.x * 256 + threadIdx.x;
    const int N = BB * CC * 2 * (HH / 2) * MM;
    if (idx >= N) return;
    int wo = idx % MM;
    int a  = (idx / MM) % (HH / 2);
    int fw = (idx / (MM * (HH / 2))) % 2;
    int bc = idx / (MM * (HH / 2) * 2);
    const float* lo = mx + ((size_t)(bc * 4 + fw * 2) * MODES) + wo;
    const float* hi = lo + MODES;
    float l[4], h4[4];
    #pragma unroll
    for (int q = 0; q < 4; ++q) {
        l[q]  = lo[(size_t)(a + q) * MM];
        h4[q] = hi[(size_t)(a + q) * MM];
    }
    float out0 = 0.f, out1 = 0.f;
    #pragma unroll
    for (int q = 0; q < 4; ++q) {
        out0 += l[q] * DEC_LO[2 * q + 1] + h4[q] * DEC_HI[2 * q + 1];  // h = 2a
        out1 += l[q] * DEC_LO[2 * q]     + h4[q] * DEC_HI[2 * q];      // h = 2a+1
    }
    size_t base = ((size_t)(bc * 2 + fw) * HH + 2 * a) * MM + wo;
    u1[base]      = out0;
    u1[base + MM] = out1;
}

// ---------------- synthesis along W: u1 -> out (B,C,128,128) ----------------
__global__ __launch_bounds__(256) void idwt_w(const float* __restrict__ u1, float* __restrict__ out) {
    int idx = blockIdx.x * 256 + threadIdx.x;
    const int N = BB * CC * HH * (WW / 2);
    if (idx >= N) return;
    int a  = idx % (WW / 2);
    int h  = (idx / (WW / 2)) % HH;
    int bc = idx / ((WW / 2) * HH);
    const float* lo = u1 + (size_t)(bc * 2) * HH * MM + (size_t)h * MM;
    const float* hi = lo + (size_t)HH * MM;
    float l[4], h4[4];
    #pragma unroll
    for (int q = 0; q < 4; ++q) {
        l[q]  = lo[a + q];
        h4[q] = hi[a + q];
    }
    float out0 = 0.f, out1 = 0.f;
    #pragma unroll
    for (int q = 0; q < 4; ++q) {
        out0 += l[q] * DEC_LO[2 * q + 1] + h4[q] * DEC_HI[2 * q + 1];  // n = 2a
        out1 += l[q] * DEC_LO[2 * q]     + h4[q] * DEC_HI[2 * q];      // n = 2a+1
    }
    float2 r = make_float2(out0, out1);
    *(float2*)&out[((size_t)bc * HH + h) * WW + 2 * a] = r;
}

extern "C" void kernel_launch(void* const* d_in, const int* in_sizes, int n_in,
                              void* d_out, int out_size, void* d_ws, size_t ws_size,
                              hipStream_t stream) {
    const float* x  = (const float*)d_in[0];
    const float* w1 = (const float*)d_in[1];
    const float* w2 = (const float*)d_in[2];
    const float* w3 = (const float*)d_in[3];
    const float* w4 = (const float*)d_in[4];
    float* out = (float*)d_out;

    const size_t COEFF_FLTS = (size_t)BB * CC * 4 * MODES;
    float* buf1 = (float*)d_ws;
    float* buf2 = buf1 + COEFF_FLTS;

    // 1) DWT along W: x -> buf1 (t1)
    {
        dim3 grid(BB * CC, HH / 8);
        dwt_w<<<grid, 256, 0, stream>>>(x, buf1);
    }
    // 2) DWT along H: buf1 -> buf2 (coeff)
    {
        int N = BB * CC * 2 * ((MM + 1) / 2) * MM;
        dwt_h<<<(N + 255) / 256, 256, 0, stream>>>(buf1, buf2);
    }
    // 3) per-mode channel mixing: buf2 -> buf1 (mixed)
    {
        dim3 grid(NCHUNK, 4);   // (141 mode-chunks, 4 bands)
        mix_k<<<grid, 512, 0, stream>>>(buf2, w1, w2, w3, w4, buf1);
    }
    // 4) inverse DWT along H: buf1 -> buf2 (u1)
    {
        int N = BB * CC * 2 * (HH / 2) * MM;
        idwt_h<<<(N + 255) / 256, 256, 0, stream>>>(buf1, buf2);
    }
    // 5) inverse DWT along W: buf2 -> d_out
    {
        int N = BB * CC * HH * (WW / 2);
        idwt_w<<<(N + 255) / 256, 256, 0, stream>>>(buf2, out);
    }
}